// Round 1
// baseline (207.683 us; speedup 1.0000x reference)
//
#include <hip/hip_runtime.h>
#include <math.h>

// MoELayerStacks: selective-expert evaluation via counting sort.
// E=8, L1=1024, L2=15, L3=32, B=32768. Only the argmax expert's MLP is
// evaluated per token (reference computes all 8 then gathers).

#define NE 8
#define NL1 1024
#define NB 32768

// ws layout (in 4-byte words)
#define WS_W1C    0        // 128*1024 floats: l1_w + tile(l1_fw)
#define WS_B1C    131072   // 128 floats
#define WS_STATS  131200   // 12 floats: tp, agree, tce, z, sum_p[8]
#define WS_COUNTS 131212   // 8 ints
#define WS_PMAX   131220   // 32768 floats: selected gate prob per token
#define WS_SORTED 163988   // 8*32768 ints: per-expert token lists

__device__ __forceinline__ float clamp01(float v) { return fminf(fmaxf(v, 0.0f), 1.0f); }

// ---------------- prep: fused l1 weights + zero accumulators ----------------
__global__ __launch_bounds__(256) void k_prep(const float* __restrict__ l1_w,
                                              const float* __restrict__ l1_fw,
                                              const float* __restrict__ l1_b,
                                              const float* __restrict__ l1_fb,
                                              float* __restrict__ ws) {
  const int r = blockIdx.x;   // 0..127 row of combined weight
  const int t = threadIdx.x;  // 0..255
  const float* src  = l1_w + r * NL1;
  const float* fsrc = l1_fw + (r & 15) * NL1;
  float* dst = ws + WS_W1C + r * NL1;
#pragma unroll
  for (int k = 0; k < 4; ++k) {
    const int i = t + k * 256;
    dst[i] = src[i] + fsrc[i];
  }
  if (r == 0) {
    if (t < 128) ws[WS_B1C + t] = l1_b[t] + l1_fb[t & 15];
    if (t >= 128 && t < 140) ws[WS_STATS + (t - 128)] = 0.0f;
    if (t >= 140 && t < 148) ((int*)ws)[WS_COUNTS + (t - 140)] = 0;
  }
}

// ---------------- router + stats + counting-sort scatter ----------------
__device__ __forceinline__ void wred_atomic(float v, float* dst) {
#pragma unroll
  for (int m = 32; m >= 1; m >>= 1) v += __shfl_xor(v, m, 64);
  if ((threadIdx.x & 63) == 0) atomicAdd(dst, v);
}

__global__ __launch_bounds__(256) void k_router(const float* __restrict__ x,
                                                const int* __restrict__ ls,
                                                const float* __restrict__ rw,
                                                const float* __restrict__ rb,
                                                float* __restrict__ ws) {
  __shared__ int hist[NE];
  __shared__ int hbase[NE];
  const int t = threadIdx.x;
  const int b = blockIdx.x * 256 + t;
  if (t < NE) hist[t] = 0;
  __syncthreads();

  // router_input = concat(x[b, 0:32], x[b, 512:544])
  float ri[64];
  const float4* xr = (const float4*)(x + (size_t)b * NL1);
#pragma unroll
  for (int q = 0; q < 8; ++q) {
    float4 v = xr[q];
    ri[q * 4 + 0] = v.x; ri[q * 4 + 1] = v.y; ri[q * 4 + 2] = v.z; ri[q * 4 + 3] = v.w;
  }
#pragma unroll
  for (int q = 0; q < 8; ++q) {
    float4 v = xr[128 + q];
    ri[32 + q * 4 + 0] = v.x; ri[32 + q * 4 + 1] = v.y; ri[32 + q * 4 + 2] = v.z; ri[32 + q * 4 + 3] = v.w;
  }

  float logits[NE];
#pragma unroll
  for (int e = 0; e < NE; ++e) {
    float s = rb[e];
    const float* w = rw + e * 64;  // uniform address -> scalar loads
#pragma unroll
    for (int k = 0; k < 64; ++k) s = fmaf(ri[k], w[k], s);
    logits[e] = s;
  }

  // argmax, first occurrence on ties (strict >), log-softmax
  float m = logits[0]; int am = 0;
#pragma unroll
  for (int e = 1; e < NE; ++e) { if (logits[e] > m) { m = logits[e]; am = e; } }
  float se = 0.0f;
#pragma unroll
  for (int e = 0; e < NE; ++e) se += expf(logits[e] - m);
  const float lse = m + logf(se);
  float p[NE];
#pragma unroll
  for (int e = 0; e < NE; ++e) p[e] = expf(logits[e] - lse);

  const int lsb = ls[b];
  // static-index selects (avoid runtime-indexed array -> scratch)
  float tp = 0.0f, lls = 0.0f, psel = 0.0f;
#pragma unroll
  for (int e = 0; e < NE; ++e) {
    tp   = (e == lsb) ? p[e] : tp;
    lls  = (e == lsb) ? logits[e] : lls;
    psel = (e == am)  ? p[e] : psel;
  }
  const float agree = (am == lsb) ? 1.0f : 0.0f;
  const float tce = lse - lls;   // -logp[ls]
  const float z = lse * lse;

  wred_atomic(tp,    &ws[WS_STATS + 0]);
  wred_atomic(agree, &ws[WS_STATS + 1]);
  wred_atomic(tce,   &ws[WS_STATS + 2]);
  wred_atomic(z,     &ws[WS_STATS + 3]);
#pragma unroll
  for (int e = 0; e < NE; ++e) wred_atomic(p[e], &ws[WS_STATS + 4 + e]);

  ws[WS_PMAX + b] = psel;

  // counting-sort scatter (order within a bucket is irrelevant)
  int* wsI = (int*)ws;
  const int lpos = atomicAdd(&hist[am], 1);
  __syncthreads();
  if (t < NE) hbase[t] = atomicAdd(&wsI[WS_COUNTS + t], hist[t]);
  __syncthreads();
  wsI[WS_SORTED + am * NB + hbase[am] + lpos] = b;
}

// ---------------- finalize scalar losses ----------------
__global__ void k_finalize(const float* __restrict__ ws, float* __restrict__ out) {
  if (threadIdx.x != 0 || blockIdx.x != 0) return;
  const float invB = 1.0f / 32768.0f;
  const int* wsI = (const int*)ws;
  float aux_floor = 0.0f, aux_cap = 0.0f;
#pragma unroll
  for (int e = 0; e < NE; ++e) {
    const float frac = (float)wsI[WS_COUNTS + e] * invB;
    const float avg  = ws[WS_STATS + 4 + e] * invB;
    const float le = avg + (frac - avg);   // mirror ref fp order
    const float f = fmaxf(0.05f - le, 0.0f);
    const float c = fmaxf(le - 0.5f, 0.0f);
    aux_floor += f * f;
    aux_cap   += c * c;
    out[32772 + e] = frac;
    out[32780 + e] = avg;
  }
  const float aux = aux_floor * 0.125f + aux_cap * 0.125f;
  const float zl  = ws[WS_STATS + 3] * invB;
  const float tce = ws[WS_STATS + 2] * invB;
  out[32768] = 0.01f * aux + 0.001f * zl + 0.5f * tce;  // router_loss
  out[32769] = aux;
  out[32770] = zl;
  out[32771] = tce;
  out[32788] = ws[WS_STATS + 0] * invB;  // target_prob
  out[32789] = ws[WS_STATS + 1] * invB;  // bucket_agreement
}

// ---------------- main expert kernel ----------------
// block = 256 threads: 64 tokens (lane l) x 4 K-slices (wave w).
// x staged global->LDS via async global_load_lds, double-buffered,
// tile = 64 tok x 128 floats (32 per slice) = 32KB; 2 buffers = 64KB LDS.
__global__ __launch_bounds__(256) void k_expert(const float* __restrict__ x,
                                                const float* __restrict__ ws,
                                                const float* __restrict__ l2_w,
                                                const float* __restrict__ l2_b,
                                                const float* __restrict__ out_w,
                                                const float* __restrict__ out_b,
                                                float* __restrict__ out) {
  __shared__ float lds[16384];
  const int t = threadIdx.x;
  const int l = t & 63;
  const int w = t >> 6;
  const int wu = __builtin_amdgcn_readfirstlane(w);  // wave-uniform -> scalar weight loads
  const int bid = blockIdx.x;
  const int e = bid >> 9;       // 512 chunks per expert
  const int c = bid & 511;
  const int* wsI = (const int*)ws;
  const int n = wsI[WS_COUNTS + e];
  const int start = c * 64;
  if (start >= n) return;       // uniform exit, before any barrier
  const bool valid = (start + l) < n;
  const int tok = valid ? wsI[WS_SORTED + e * NB + start + l] : 0;
  const float* __restrict__ xrow = x + (size_t)tok * NL1;
  const float* __restrict__ W = ws + WS_W1C + e * 16 * NL1;

  float acc[16];
#pragma unroll
  for (int o = 0; o < 16; ++o) acc[o] = (w == 0) ? ws[WS_B1C + e * 16 + o] : 0.0f;

  // LDS float4-slot F = qhat*256 + slice*64 + tk  (conflict-free b128 reads).
  // Stage inst (wave wu, j): qhat = 2*wu + (j>>2), slice = j&3, lane = token.
#define STAGE(bp, tau)                                                          \
  do {                                                                          \
    _Pragma("unroll")                                                           \
    for (int j = 0; j < 8; ++j) {                                               \
      const int col = ((j & 3) << 8) + ((tau) << 5) + (((wu << 1) + (j >> 2)) << 2); \
      const float* gp = xrow + col;                                             \
      float* lp = &lds[(bp) * 8192 + wu * 2048 + j * 256];                      \
      __builtin_amdgcn_global_load_lds(                                         \
          (const __attribute__((address_space(1))) void*)gp,                    \
          (__attribute__((address_space(3))) void*)lp, 16, 0, 0);               \
    }                                                                           \
  } while (0)

#define COMPUTE(bp, tau)                                                        \
  do {                                                                          \
    _Pragma("unroll")                                                           \
    for (int q = 0; q < 8; ++q) {                                               \
      const float4 xv = *(const float4*)&lds[(bp) * 8192 + q * 1024 + wu * 256 + (l << 2)]; \
      const int colb = (wu << 8) + ((tau) << 5) + (q << 2);                     \
      _Pragma("unroll")                                                         \
      for (int o = 0; o < 16; ++o) {                                            \
        const float4 wv = *(const float4*)&W[o * NL1 + colb];                   \
        acc[o] = fmaf(xv.x, wv.x, acc[o]);                                      \
        acc[o] = fmaf(xv.y, wv.y, acc[o]);                                      \
        acc[o] = fmaf(xv.z, wv.z, acc[o]);                                      \
        acc[o] = fmaf(xv.w, wv.w, acc[o]);                                      \
      }                                                                         \
    }                                                                           \
  } while (0)

  STAGE(0, 0);
  asm volatile("s_waitcnt vmcnt(0)" ::: "memory");
  __syncthreads();
#pragma unroll 2
  for (int tau = 0; tau < 8; ++tau) {
    if (tau < 7) { STAGE((tau + 1) & 1, tau + 1); }
    COMPUTE(tau & 1, tau);
    asm volatile("s_waitcnt vmcnt(0)" ::: "memory");
    __syncthreads();
  }
#undef STAGE
#undef COMPUTE

  // cross-slice reduction: red[tk][o*4 + s], row pad 65 (bank-spread)
#pragma unroll
  for (int o = 0; o < 16; ++o) lds[l * 65 + o * 4 + w] = acc[o];
  __syncthreads();

  if (w == 0) {
    float tot[16];
#pragma unroll
    for (int o = 0; o < 16; ++o)
      tot[o] = (lds[l * 65 + o * 4 + 0] + lds[l * 65 + o * 4 + 1]) +
               (lds[l * 65 + o * 4 + 2] + lds[l * 65 + o * 4 + 3]);

    // act = clip(concat(l1x^2*255/256, l1x), 0, 1)
    float act[30];
#pragma unroll
    for (int j = 0; j < 15; ++j) {
      const float v = tot[j];
      act[j]      = clamp01(v * v * (255.0f / 256.0f));
      act[15 + j] = clamp01(v);
    }
    float y = out_b[e];
    const float* w2r = l2_w + e * 32 * 30;
    const float* w3r = out_w + e * 32;
#pragma unroll 4
    for (int m2 = 0; m2 < 32; ++m2) {
      float s2 = l2_b[e * 32 + m2];
#pragma unroll
      for (int j = 0; j < 30; ++j) s2 = fmaf(act[j], w2r[m2 * 30 + j], s2);
      s2 = clamp01(s2);
      y = fmaf(s2, w3r[m2], y);
    }
    float sel = y + tot[15];  // + l1x_out
    const float pg = ws[WS_PMAX + tok];
    sel *= (1.0f + pg) - pg;  // mirror ref fp order (numerically ~1)
    if (valid) out[tok] = sel;
  }
}

extern "C" void kernel_launch(void* const* d_in, const int* in_sizes, int n_in,
                              void* d_out, int out_size, void* d_ws, size_t ws_size,
                              hipStream_t stream) {
  const float* x     = (const float*)d_in[0];
  const int*   ls    = (const int*)d_in[1];
  const float* rw    = (const float*)d_in[2];
  const float* rb    = (const float*)d_in[3];
  const float* l1_w  = (const float*)d_in[4];
  const float* l1_fw = (const float*)d_in[5];
  const float* l1_b  = (const float*)d_in[6];
  const float* l1_fb = (const float*)d_in[7];
  const float* l2_w  = (const float*)d_in[8];
  const float* l2_b  = (const float*)d_in[9];
  const float* out_w = (const float*)d_in[10];
  const float* out_b = (const float*)d_in[11];
  float* out = (float*)d_out;
  float* ws  = (float*)d_ws;

  k_prep<<<dim3(128), dim3(256), 0, stream>>>(l1_w, l1_fw, l1_b, l1_fb, ws);
  k_router<<<dim3(128), dim3(256), 0, stream>>>(x, ls, rw, rb, ws);
  k_finalize<<<dim3(1), dim3(64), 0, stream>>>(ws, out);
  k_expert<<<dim3(4096), dim3(256), 0, stream>>>(x, ws, l2_w, l2_b, out_w, out_b, out);
}

// Round 3
// 58.334 us; speedup vs baseline: 3.5602x; 3.5602x over previous
//
#include <hip/hip_runtime.h>
#include <math.h>

// MoELayerStacks: selective-expert evaluation via counting sort + bf16 MFMA.
// E=8, L1=1024, L2=15, L3=32, B=32768.

#define NE 8
#define NL1 1024
#define NB 32768
#define NCH 512         // chunks per expert (capacity 16384 tokens)
#define NTOK 32         // tokens per chunk

// ws layout (4-byte words)
#define WS_W1C    0        // 128*1024 floats: l1_w + tile(l1_fw)
#define WS_B1C    131072   // 128 floats
#define WS_COUNTS 131200   // 8 ints
#define WS_PART   131208   // 128 blocks * 12 floats partial stats
#define WS_PMAX   132744   // 32768 floats: selected gate prob per token
#define WS_SORTED 165512   // 8*32768 ints: per-expert token lists

typedef __attribute__((ext_vector_type(4))) float f32x4;
typedef __attribute__((ext_vector_type(8))) short bf16x8;
typedef __attribute__((ext_vector_type(4))) unsigned u32x4;

__device__ __forceinline__ float clamp01(float v) { return fminf(fmaxf(v, 0.0f), 1.0f); }

// pack 8 fp32 -> bf16x8 (element i = k-offset i); A and B sides both use this,
// so the MFMA-internal k mapping cancels (A/B fragment symmetry).
__device__ __forceinline__ bf16x8 cvt8(float4 lo, float4 hi) {
  unsigned p0, p1, p2, p3;
  asm("v_cvt_pk_bf16_f32 %0, %1, %2" : "=v"(p0) : "v"(lo.x), "v"(lo.y));
  asm("v_cvt_pk_bf16_f32 %0, %1, %2" : "=v"(p1) : "v"(lo.z), "v"(lo.w));
  asm("v_cvt_pk_bf16_f32 %0, %1, %2" : "=v"(p2) : "v"(hi.x), "v"(hi.y));
  asm("v_cvt_pk_bf16_f32 %0, %1, %2" : "=v"(p3) : "v"(hi.z), "v"(hi.w));
  u32x4 u; u.x = p0; u.y = p1; u.z = p2; u.w = p3;
  return __builtin_bit_cast(bf16x8, u);
}

// ---------------- prep: fused l1 weights + zero counters ----------------
__global__ __launch_bounds__(256) void k_prep(const float* __restrict__ l1_w,
                                              const float* __restrict__ l1_fw,
                                              const float* __restrict__ l1_b,
                                              const float* __restrict__ l1_fb,
                                              float* __restrict__ ws) {
  const int r = blockIdx.x;   // 0..127
  const int t = threadIdx.x;  // 0..255
  const float* src  = l1_w + r * NL1;
  const float* fsrc = l1_fw + (r & 15) * NL1;
  float* dst = ws + WS_W1C + r * NL1;
#pragma unroll
  for (int k = 0; k < 4; ++k) {
    const int i = t + k * 256;
    dst[i] = src[i] + fsrc[i];
  }
  if (r == 0) {
    if (t < 128) ws[WS_B1C + t] = l1_b[t] + l1_fb[t & 15];
    if (t >= 128 && t < 136) ((int*)ws)[WS_COUNTS + (t - 128)] = 0;
  }
}

// ---------------- router + stats + counting-sort scatter ----------------
__device__ __forceinline__ float wsum(float v) {
#pragma unroll
  for (int m = 32; m >= 1; m >>= 1) v += __shfl_xor(v, m, 64);
  return v;
}

__global__ __launch_bounds__(256) void k_router(const float* __restrict__ x,
                                                const int* __restrict__ ls,
                                                const float* __restrict__ rw,
                                                const float* __restrict__ rb,
                                                float* __restrict__ ws) {
  __shared__ float part[4][12];
  __shared__ int hist[NE];
  __shared__ int hbase[NE];
  const int t = threadIdx.x;
  const int w = t >> 6;
  const int b = blockIdx.x * 256 + t;
  if (t < NE) hist[t] = 0;
  __syncthreads();

  float ri[64];
  const float4* xr = (const float4*)(x + (size_t)b * NL1);
#pragma unroll
  for (int q = 0; q < 8; ++q) {
    float4 v = xr[q];
    ri[q * 4 + 0] = v.x; ri[q * 4 + 1] = v.y; ri[q * 4 + 2] = v.z; ri[q * 4 + 3] = v.w;
  }
#pragma unroll
  for (int q = 0; q < 8; ++q) {
    float4 v = xr[128 + q];
    ri[32 + q * 4 + 0] = v.x; ri[32 + q * 4 + 1] = v.y; ri[32 + q * 4 + 2] = v.z; ri[32 + q * 4 + 3] = v.w;
  }

  float logits[NE];
#pragma unroll
  for (int e = 0; e < NE; ++e) {
    float s = rb[e];
    const float* wv = rw + e * 64;  // uniform -> scalar loads
#pragma unroll
    for (int k = 0; k < 64; ++k) s = fmaf(ri[k], wv[k], s);
    logits[e] = s;
  }

  float m = logits[0]; int am = 0;
#pragma unroll
  for (int e = 1; e < NE; ++e) { if (logits[e] > m) { m = logits[e]; am = e; } }
  float se = 0.0f;
#pragma unroll
  for (int e = 0; e < NE; ++e) se += expf(logits[e] - m);
  const float lse = m + logf(se);
  float p[NE];
#pragma unroll
  for (int e = 0; e < NE; ++e) p[e] = expf(logits[e] - lse);

  const int lsb = ls[b];
  float tp = 0.0f, lls = 0.0f, psel = 0.0f;
#pragma unroll
  for (int e = 0; e < NE; ++e) {
    tp   = (e == lsb) ? p[e] : tp;
    lls  = (e == lsb) ? logits[e] : lls;
    psel = (e == am)  ? p[e] : psel;
  }
  const float agree = (am == lsb) ? 1.0f : 0.0f;
  const float tce = lse - lls;
  const float z = lse * lse;

  ws[WS_PMAX + b] = psel;

  int* wsI = (int*)ws;
  const int lpos = atomicAdd(&hist[am], 1);

  // per-wave reductions, no global float atomics
  const float sA = wsum(tp), sB = wsum(agree), sC = wsum(tce), sD = wsum(z);
  const float q0 = wsum(p[0]), q1 = wsum(p[1]), q2 = wsum(p[2]), q3 = wsum(p[3]);
  const float q4 = wsum(p[4]), q5 = wsum(p[5]), q6 = wsum(p[6]), q7 = wsum(p[7]);
  if ((t & 63) == 0) {
    part[w][0] = sA; part[w][1] = sB; part[w][2]  = sC; part[w][3]  = sD;
    part[w][4] = q0; part[w][5] = q1; part[w][6]  = q2; part[w][7]  = q3;
    part[w][8] = q4; part[w][9] = q5; part[w][10] = q6; part[w][11] = q7;
  }
  __syncthreads();
  if (t < 12) ws[WS_PART + blockIdx.x * 12 + t] =
      (part[0][t] + part[1][t]) + (part[2][t] + part[3][t]);
  if (t < NE) hbase[t] = atomicAdd(&wsI[WS_COUNTS + t], hist[t]);
  __syncthreads();
  wsI[WS_SORTED + am * NB + hbase[am] + lpos] = b;
}

// ---------------- finalize scalar losses ----------------
__global__ void k_finalize(const float* __restrict__ ws, float* __restrict__ out) {
  __shared__ float red[12][16];
  const int t = threadIdx.x;  // 256
  if (t < 192) {
    const int s = t >> 4, j = t & 15;
    float v = 0.0f;
#pragma unroll
    for (int m = 0; m < 8; ++m) v += ws[WS_PART + (j + 16 * m) * 12 + s];
    red[s][j] = v;
  }
  __syncthreads();
  if (t == 0) {
    float st[12];
#pragma unroll
    for (int s = 0; s < 12; ++s) {
      float v = 0.0f;
#pragma unroll
      for (int j = 0; j < 16; ++j) v += red[s][j];
      st[s] = v;
    }
    const float invB = 1.0f / 32768.0f;
    const int* wsI = (const int*)ws;
    float aux_floor = 0.0f, aux_cap = 0.0f;
#pragma unroll
    for (int e = 0; e < NE; ++e) {
      const float frac = (float)wsI[WS_COUNTS + e] * invB;
      const float avg  = st[4 + e] * invB;
      const float le = avg + (frac - avg);
      const float f = fmaxf(0.05f - le, 0.0f);
      const float c = fmaxf(le - 0.5f, 0.0f);
      aux_floor += f * f;
      aux_cap   += c * c;
      out[32772 + e] = frac;
      out[32780 + e] = avg;
    }
    const float aux = aux_floor * 0.125f + aux_cap * 0.125f;
    const float zl  = st[3] * invB;
    const float tce = st[2] * invB;
    out[32768] = 0.01f * aux + 0.001f * zl + 0.5f * tce;
    out[32769] = aux;
    out[32770] = zl;
    out[32771] = tce;
    out[32788] = st[0] * invB;
    out[32789] = st[1] * invB;
  }
}

// ---------------- main expert kernel (bf16 MFMA builtin, K-split 4 waves) ------
// block = 256 threads = 4 waves; 32 tokens/block; wave w owns k in [256w,256w+256).
// x staged fp32 -> LDS via global_load_lds (linear dest, XOR-swizzled source);
// per tau: 128 swizzled floats/token; wave w consumes logical l in [32w,32w+32)
// = global k [256w+32*tau, +32). Physical float4-slot p in row r holds logical
// 4*(p^r). Weights held in registers as bf16 B-fragments (mirrored k-order).
__global__ __launch_bounds__(256) void k_expert(const float* __restrict__ x,
                                                const float* __restrict__ ws,
                                                const float* __restrict__ l2_w,
                                                const float* __restrict__ l2_b,
                                                const float* __restrict__ out_w,
                                                const float* __restrict__ out_b,
                                                float* __restrict__ out) {
  __shared__ float lds[8192];
  const int t = threadIdx.x;
  const int l = t & 63;
  const int w = t >> 6;
  const int bid = blockIdx.x;
  const int e = bid >> 9;       // NCH=512
  const int c = bid & 511;
  const int* wsI = (const int*)ws;
  const int n = wsI[WS_COUNTS + e];
  const int start = c * NTOK;
  if (start >= n) return;       // uniform exit, before any barrier

  const int g = l >> 4;          // 0..3 (k lane-group)
  const int r0 = l & 15;         // acc0 token row
  const int r1 = r0 + 16;        // acc1 token row

  // ---- B fragments: 8 steps of k=32, loaded once; elem (g,i)=W[n][K0+8g+i] ----
  const float* We = ws + WS_W1C + e * 16 * NL1;
  const float* Wr = We + r0 * NL1 + 256 * w + 8 * g;   // r0 = output index n
  bf16x8 bfrag[8];
#pragma unroll
  for (int st2 = 0; st2 < 8; ++st2) {
    const float4 blo = *(const float4*)&Wr[32 * st2];
    const float4 bhi = *(const float4*)&Wr[32 * st2 + 4];
    bfrag[st2] = cvt8(blo, bhi);
  }

  // ---- staging source pointers (4 global_load_lds per wave per tau) ----
  const int lam = l & 31;
  const int lh  = l >> 5;
  const float* srcp[4];
#pragma unroll
  for (int j = 0; j < 4; ++j) {
    const int tl = 8 * w + 2 * j + lh;              // tile-local token 0..31
    int pos = start + tl; if (pos > n - 1) pos = n - 1;
    const int tokid = wsI[WS_SORTED + e * NB + pos];
    const int cc = (4 * lam) ^ (tl << 2);           // logical col (swizzle inverse)
    srcp[j] = x + (size_t)tokid * NL1 + 256 * (cc >> 5) + (cc & 31);
  }

  // ---- A-read addresses (swizzled): slots q0,q0^1 hold k-elems 0-3,4-7 ----
  const int q0 = (8 * w + 2 * g) ^ r0;
  const int q1 = (8 * w + 2 * g) ^ r1;
  const int a0lo = r0 * 128 + 4 * q0,        a0hi = r0 * 128 + 4 * (q0 ^ 1);
  const int a1lo = r1 * 128 + 4 * q1,        a1hi = r1 * 128 + 4 * (q1 ^ 1);

#define STAGE(buf, tau) do {                                                    \
  _Pragma("unroll")                                                             \
  for (int j = 0; j < 4; ++j) {                                                 \
    __builtin_amdgcn_global_load_lds(                                           \
        (const __attribute__((address_space(1))) void*)(srcp[j] + 32 * (tau)),  \
        (__attribute__((address_space(3))) void*)&lds[(buf) * 4096 + w * 1024 + j * 256], \
        16, 0, 0);                                                              \
  } } while (0)

#define COMPUTE(buf, tau) do {                                                  \
    const float* Lp = &lds[(buf) * 4096];                                       \
    const float4 v0l = *(const float4*)&Lp[a0lo];                               \
    const float4 v0h = *(const float4*)&Lp[a0hi];                               \
    const float4 v1l = *(const float4*)&Lp[a1lo];                               \
    const float4 v1h = *(const float4*)&Lp[a1hi];                               \
    acc0 = __builtin_amdgcn_mfma_f32_16x16x32_bf16(cvt8(v0l, v0h), bfrag[tau], acc0, 0, 0, 0); \
    acc1 = __builtin_amdgcn_mfma_f32_16x16x32_bf16(cvt8(v1l, v1h), bfrag[tau], acc1, 0, 0, 0); \
  } while (0)

  f32x4 acc0 = {0.f, 0.f, 0.f, 0.f};
  f32x4 acc1 = {0.f, 0.f, 0.f, 0.f};

  STAGE(0, 0);
#pragma unroll
  for (int tau = 0; tau < 8; ++tau) {
    if (tau < 7) {
      STAGE((tau + 1) & 1, tau + 1);
      asm volatile("s_waitcnt vmcnt(4)" ::: "memory");   // tau's loads done; prefetch alive
    } else {
      asm volatile("s_waitcnt vmcnt(0)" ::: "memory");
    }
    __builtin_amdgcn_sched_barrier(0);
    __builtin_amdgcn_s_barrier();
    __builtin_amdgcn_sched_barrier(0);
    COMPUTE(tau & 1, tau);
    __builtin_amdgcn_sched_barrier(0);
    __builtin_amdgcn_s_barrier();     // protect buffer about to be re-staged
    __builtin_amdgcn_sched_barrier(0);
  }
#undef STAGE
#undef COMPUTE

  __syncthreads();
  // cross-wave reduce: lds[w*544 + tok*17 + out]; D layout: tok=4*(l>>4)+r, out=l&15
#pragma unroll
  for (int r = 0; r < 4; ++r) {
    const int tk0 = 4 * (l >> 4) + r;
    lds[w * 544 + tk0 * 17 + (l & 15)]        = acc0[r];
    lds[w * 544 + (16 + tk0) * 17 + (l & 15)] = acc1[r];
  }
  __syncthreads();
#pragma unroll
  for (int pi = 0; pi < 2; ++pi) {
    const int p = t + pi * 256;
    const int tok = p >> 4, o = p & 15;
    float v = (lds[0 * 544 + tok * 17 + o] + lds[1 * 544 + tok * 17 + o]) +
              (lds[2 * 544 + tok * 17 + o] + lds[3 * 544 + tok * 17 + o]);
    v += ws[WS_B1C + e * 16 + o];
    lds[2176 + tok * 17 + o] = v;
  }
  __syncthreads();

  if (t < NTOK) {
    const bool valid = (start + t) < n;
    int pos = start + t; if (pos > n - 1) pos = n - 1;
    const int tokid = wsI[WS_SORTED + e * NB + pos];
    float tot[16];
#pragma unroll
    for (int o = 0; o < 16; ++o) tot[o] = lds[2176 + t * 17 + o];

    float act[30];
#pragma unroll
    for (int j = 0; j < 15; ++j) {
      const float v = tot[j];
      act[j]      = clamp01(v * v * (255.0f / 256.0f));
      act[15 + j] = clamp01(v);
    }
    float y = out_b[e];
    const float* w2r = l2_w + e * 32 * 30;
    const float* w3r = out_w + e * 32;
#pragma unroll 4
    for (int m2 = 0; m2 < 32; ++m2) {
      float s2 = l2_b[e * 32 + m2];
#pragma unroll
      for (int j = 0; j < 30; ++j) s2 = fmaf(act[j], w2r[m2 * 30 + j], s2);
      s2 = clamp01(s2);
      y = fmaf(s2, w3r[m2], y);
    }
    float sel = y + tot[15];
    const float pg = ws[WS_PMAX + tokid];
    sel *= (1.0f + pg) - pg;
    if (valid) out[tokid] = sel;
  }
}

extern "C" void kernel_launch(void* const* d_in, const int* in_sizes, int n_in,
                              void* d_out, int out_size, void* d_ws, size_t ws_size,
                              hipStream_t stream) {
  const float* x     = (const float*)d_in[0];
  const int*   ls    = (const int*)d_in[1];
  const float* rw    = (const float*)d_in[2];
  const float* rb    = (const float*)d_in[3];
  const float* l1_w  = (const float*)d_in[4];
  const float* l1_fw = (const float*)d_in[5];
  const float* l1_b  = (const float*)d_in[6];
  const float* l1_fb = (const float*)d_in[7];
  const float* l2_w  = (const float*)d_in[8];
  const float* l2_b  = (const float*)d_in[9];
  const float* out_w = (const float*)d_in[10];
  const float* out_b = (const float*)d_in[11];
  float* out = (float*)d_out;
  float* ws  = (float*)d_ws;

  k_prep<<<dim3(128), dim3(256), 0, stream>>>(l1_w, l1_fw, l1_b, l1_fb, ws);
  k_router<<<dim3(128), dim3(256), 0, stream>>>(x, ls, rw, rb, ws);
  k_finalize<<<dim3(1), dim3(256), 0, stream>>>(ws, out);
  k_expert<<<dim3(4096), dim3(256), 0, stream>>>(x, ws, l2_w, l2_b, out_w, out_b, out);
}